// Round 7
// baseline (146.832 us; speedup 1.0000x reference)
//
#include <hip/hip_runtime.h>
#include <hip/hip_bf16.h>

typedef __attribute__((ext_vector_type(8))) short short8;
typedef __attribute__((ext_vector_type(4))) float f32x4;
typedef __attribute__((ext_vector_type(4))) unsigned int uint4v;

#define SWZ(r) (((r) & 7) << 4)   // XOR-swizzle of 16B slot within 8-row stripe

__device__ __forceinline__ unsigned short f2bf_rne(float x) {
  unsigned u = __float_as_uint(x);
  return (unsigned short)((u + 0x7FFFu + ((u >> 16) & 1u)) >> 16);
}
// scalar cast the compiler fuses into v_cvt_pk_bf16_f32 pairs (m240)
__device__ __forceinline__ short bfc(float x) {
  __hip_bfloat16 h = __float2bfloat16(x);
  return __builtin_bit_cast(short, h);
}
// async global->LDS, 16B per lane; LDS dest = uniform base + lane*16 (HW),
// so swizzled layouts are achieved by pre-swizzling the GLOBAL source (m173).
__device__ __forceinline__ void gload_lds16(const void* g, void* l) {
  __builtin_amdgcn_global_load_lds(
      (const __attribute__((address_space(1))) void*)g,
      (__attribute__((address_space(3))) void*)l, 16, 0, 0);
}

// ---- prep: weights -> bf16, fragment-transposed into d_ws (once per launch) ----
__global__ __launch_bounds__(256) void prep_kernel(
    const float* __restrict__ gW0, const float* __restrict__ gW1,
    unsigned short* __restrict__ W0T, unsigned short* __restrict__ W1T)
{
  const int t = blockIdx.x * 256 + threadIdx.x;  // 0..65535
  {
    const int c = t >> 7, k = t & 127;
    const int src = (k + ((c >= 256) ? 128 : 0)) * 256 + (c & 255);
    W0T[t] = f2bf_rne(gW0[src]);
  }
  {
    const int n = t >> 8, k = t & 255;
    W1T[t] = f2bf_rne(gW1[k * 256 + n]);   // W1T[n][k], rows of 512B
  }
}

// ---- main: per-batch pair MLP + pooled sum ----
// Structure (round 7): M-split across waves (wave w owns i in {4w..4w+3});
// gW1 staged per 64-col quarter into LDS (double-buffered, shared by all
// waves) -- weights never need to be register-resident, which rounds 3-6
// proved the allocator refuses to do. A kept in LDS as bf16 (halves the
// broadcast ds_read traffic); C rows per-lane in f32 registers (creg).
__global__ __launch_bounds__(256, 2) void pair_kernel(
    const float* __restrict__ state,
    const unsigned short* __restrict__ W0T, const float* __restrict__ gb0,
    const unsigned short* __restrict__ W1T, const float* __restrict__ gb1,
    float* __restrict__ pooled)
{
  const int b   = blockIdx.x;
  const int tid = threadIdx.x;
  const int w   = tid >> 6;   // wave 0..3
  const int l   = tid & 63;
  const int lr  = l & 15;
  const int lg  = l >> 4;

  // LDS map: [0,8K) A bf16 [16][256]; [8K,40K) buf0; [40K,72K) buf1 (C overlays buf1)
  __shared__ __align__(16) char smem[8192 + 65536];
  char* bufs  = smem + 8192;
  char* Cbase = bufs + 32768;

  // stage quarter 0 into buf0 immediately (L2 latency hides under phase 2)
  {
    const char* src = (const char*)W1T;
    const int y0 = w * 8192 + l * 16;
    #pragma unroll
    for (int it = 0; it < 8; ++it) {
      const int y = y0 + it * 1024;
      gload_lds16(src + (y ^ SWZ(y >> 9)), bufs + (w * 8192 + it * 1024));
    }
  }

  const float* stb = state + (size_t)b * 2048;

  // ---------------- Phase 2: [A|C] = state[16x128] @ W0 ----------------
  short8 sfrag[4];
  #pragma unroll
  for (int kk = 0; kk < 4; ++kk) {
    const float* sp = stb + lr * 128 + kk * 32 + lg * 8;
    f32x4 s0 = *(const f32x4*)sp;
    f32x4 s1 = *(const f32x4*)(sp + 4);
    short8 f;
    f[0] = bfc(s0[0]); f[1] = bfc(s0[1]); f[2] = bfc(s0[2]); f[3] = bfc(s0[3]);
    f[4] = bfc(s1[0]); f[5] = bfc(s1[1]); f[6] = bfc(s1[2]); f[7] = bfc(s1[3]);
    sfrag[kk] = f;
  }

  const f32x4 z4 = {0.f, 0.f, 0.f, 0.f};
  f32x4 acc2[8];
  #pragma unroll
  for (int nt = 0; nt < 8; ++nt) acc2[nt] = z4;

  #pragma unroll
  for (int nt = 0; nt < 8; ++nt) {
    const int col = 128 * w + 16 * nt + lr;       // [A|C] col in [0,512)
    #pragma unroll
    for (int kk = 0; kk < 4; ++kk) {
      short8 bf = *(const short8*)(W0T + (size_t)col * 128 + kk * 32 + lg * 8);
      acc2[nt] = __builtin_amdgcn_mfma_f32_16x16x32_bf16(sfrag[kk], bf, acc2[nt], 0, 0, 0);
    }
  }

  // store phase-2: A as bf16 (+gb0 folded), C as f32 XOR-swizzled into buf1
  #pragma unroll
  for (int nt = 0; nt < 8; ++nt) {
    const int col = 128 * w + 16 * nt + lr;
    const float gb = gb0[col & 255];            // used only when col<256
    #pragma unroll
    for (int r = 0; r < 4; ++r) {
      const int row = lg * 4 + r;               // C/D layout: col=lr-ish, row=lg*4+r
      const float v = acc2[nt][r];
      if (col < 256) {
        *(unsigned short*)(smem + row * 512 + col * 2) = f2bf_rne(v + gb);
      } else {
        const int c2 = col - 256;
        *(float*)(Cbase + ((row * 1024 + c2 * 4) ^ SWZ(row))) = v;
      }
    }
  }
  __syncthreads();

  // C rows -> registers: lane (lr,lg) holds C[lr][kk*32+lg*8 .. +8], kk=0..7
  f32x4 creg[16];
  #pragma unroll
  for (int kk = 0; kk < 8; ++kk) {
    const int base = lr * 1024 + kk * 128 + lg * 32;
    creg[2 * kk]     = *(const f32x4*)(Cbase + ((base)      ^ SWZ(lr)));
    creg[2 * kk + 1] = *(const f32x4*)(Cbase + ((base + 16) ^ SWZ(lr)));
  }
  __syncthreads();   // creg captured everywhere; buf1 may now be overwritten

  // ---------------- Phase 3: 4 N-quarters, M-split across waves ----------------
  float pp[16];
  #pragma unroll
  for (int q = 0; q < 16; ++q) pp[q] = 0.f;

  #pragma unroll
  for (int nq = 0; nq < 4; ++nq) {
    char* cur = bufs + (nq & 1) * 32768;
    if (nq < 3) {  // stage next quarter into the other buffer (async)
      char* nxt = bufs + ((nq + 1) & 1) * 32768;
      const char* src = (const char*)W1T + (nq + 1) * 32768;
      const int y0 = w * 8192 + l * 16;
      #pragma unroll
      for (int it = 0; it < 8; ++it) {
        const int y = y0 + it * 1024;
        gload_lds16(src + (y ^ SWZ(y >> 9)), nxt + (w * 8192 + it * 1024));
      }
    }

    float gbv[4];
    #pragma unroll
    for (int nt = 0; nt < 4; ++nt) gbv[nt] = gb1[nq * 64 + nt * 16 + lr];

    f32x4 acc[4][4];
    #pragma unroll
    for (int i2 = 0; i2 < 4; ++i2)
      #pragma unroll
      for (int nt = 0; nt < 4; ++nt) acc[i2][nt] = z4;

    #pragma unroll
    for (int kk = 0; kk < 8; ++kk) {
      short8 bwf[4];
      #pragma unroll
      for (int nt = 0; nt < 4; ++nt) {
        const int off = ((nt * 16 + lr) * 512 + kk * 64 + lg * 16) ^ SWZ(lr);
        bwf[nt] = *(const short8*)(cur + off);
      }
      #pragma unroll
      for (int i2 = 0; i2 < 4; ++i2) {
        const int i = w * 4 + i2;
        uint4v ad = *(const uint4v*)(smem + i * 512 + kk * 64 + lg * 16);  // bf16 A, bcast
        f32x4 a0, a1;
        a0[0] = __uint_as_float(ad[0] << 16);
        a0[1] = __uint_as_float(ad[0] & 0xFFFF0000u);
        a0[2] = __uint_as_float(ad[1] << 16);
        a0[3] = __uint_as_float(ad[1] & 0xFFFF0000u);
        a1[0] = __uint_as_float(ad[2] << 16);
        a1[1] = __uint_as_float(ad[2] & 0xFFFF0000u);
        a1[2] = __uint_as_float(ad[3] << 16);
        a1[3] = __uint_as_float(ad[3] & 0xFFFF0000u);
        f32x4 s0 = __builtin_elementwise_max(a0 + creg[2 * kk],     z4);
        f32x4 s1 = __builtin_elementwise_max(a1 + creg[2 * kk + 1], z4);
        short8 u;
        u[0] = bfc(s0[0]); u[1] = bfc(s0[1]); u[2] = bfc(s0[2]); u[3] = bfc(s0[3]);
        u[4] = bfc(s1[0]); u[5] = bfc(s1[1]); u[6] = bfc(s1[2]); u[7] = bfc(s1[3]);
        #pragma unroll
        for (int nt = 0; nt < 4; ++nt)
          acc[i2][nt] = __builtin_amdgcn_mfma_f32_16x16x32_bf16(u, bwf[nt], acc[i2][nt], 0, 0, 0);
      }
    }

    // epilogue: relu+bias, mask (i,i) filler, accumulate pp
    #pragma unroll
    for (int nt = 0; nt < 4; ++nt) {
      float s = 0.f;
      #pragma unroll
      for (int i2 = 0; i2 < 4; ++i2) {
        const int i = w * 4 + i2;
        #pragma unroll
        for (int r = 0; r < 4; ++r) {
          const int row = lg * 4 + r;       // = j
          const float v = fmaxf(acc[i2][nt][r] + gbv[nt], 0.f);
          s += (row == i) ? 0.f : v;
        }
      }
      pp[nq * 4 + nt] += s;
    }
    __syncthreads();   // cur fully consumed; next staged buffer ready after this
  }

  // cross-wave pooled reduce (buf0 region is free now)
  float* pool = (float*)bufs;
  #pragma unroll
  for (int nq = 0; nq < 4; ++nq) {
    #pragma unroll
    for (int nt = 0; nt < 4; ++nt) {
      float v = pp[nq * 4 + nt];
      v += __shfl_xor(v, 16);
      v += __shfl_xor(v, 32);
      if (lg == 0) pool[w * 256 + nq * 64 + nt * 16 + lr] = v;
    }
  }
  __syncthreads();
  pooled[(size_t)b * 256 + tid] =
      pool[tid] + pool[256 + tid] + pool[512 + tid] + pool[768 + tid];
}

// ---- f-MLP: 8 batches per block -> 8x weight reuse per load ----
__global__ __launch_bounds__(256) void fmlp_kernel(
    const float* __restrict__ pooled,
    const float* __restrict__ fW0, const float* __restrict__ fb0,
    const float* __restrict__ fW1, const float* __restrict__ fb1,
    float* __restrict__ out)
{
  const int tid = threadIdx.x;
  const size_t b0 = (size_t)blockIdx.x * 8;
  __shared__ float pl[8][256];
  __shared__ float h1[8][256];

  #pragma unroll
  for (int q = 0; q < 8; ++q) {
    const int idx = q * 256 + tid;
    pl[idx >> 8][idx & 255] = pooled[b0 * 256 + idx];
  }
  __syncthreads();

  float acc[8] = {0.f, 0.f, 0.f, 0.f, 0.f, 0.f, 0.f, 0.f};
  #pragma unroll 4
  for (int k = 0; k < 256; ++k) {
    const float wv = fW0[(size_t)k * 256 + tid];
    #pragma unroll
    for (int q = 0; q < 8; ++q) acc[q] = fmaf(pl[q][k], wv, acc[q]);
  }
  #pragma unroll
  for (int q = 0; q < 8; ++q) h1[q][tid] = fmaxf(acc[q] + fb0[tid], 0.f);
  __syncthreads();

  float acc2[8] = {0.f, 0.f, 0.f, 0.f, 0.f, 0.f, 0.f, 0.f};
  #pragma unroll 4
  for (int k = 0; k < 256; ++k) {
    const float wv = fW1[(size_t)k * 256 + tid];
    #pragma unroll
    for (int q = 0; q < 8; ++q) acc2[q] = fmaf(h1[q][k], wv, acc2[q]);
  }
  #pragma unroll
  for (int q = 0; q < 8; ++q)
    out[(b0 + q) * 256 + tid] = fmaxf(acc2[q] + fb1[tid], 0.f);
}

extern "C" void kernel_launch(void* const* d_in, const int* in_sizes, int n_in,
                              void* d_out, int out_size, void* d_ws, size_t ws_size,
                              hipStream_t stream) {
  const float* state = (const float*)d_in[0];
  const float* gW0   = (const float*)d_in[1];
  const float* gb0   = (const float*)d_in[2];
  const float* gW1   = (const float*)d_in[3];
  const float* gb1   = (const float*)d_in[4];
  const float* fW0   = (const float*)d_in[5];
  const float* fb0   = (const float*)d_in[6];
  const float* fW1   = (const float*)d_in[7];
  const float* fb1   = (const float*)d_in[8];
  float* out = (float*)d_out;

  unsigned short* W0T = (unsigned short*)d_ws;          // 512*128 bf16 = 128KB
  unsigned short* W1T = W0T + 512 * 128;                // 256*256 bf16 = 128KB
  float* pooled = (float*)(W1T + 256 * 256);            // 1024*256 f32 = 1MB

  const int Bn = in_sizes[0] / 2048;  // 1024

  prep_kernel<<<dim3(256), dim3(256), 0, stream>>>(gW0, gW1, W0T, W1T);
  pair_kernel<<<dim3(Bn), dim3(256), 0, stream>>>(state, W0T, gb0, W1T, gb1, pooled);
  fmlp_kernel<<<dim3(Bn / 8), dim3(256), 0, stream>>>(pooled, fW0, fb0, fW1, fb1, out);
}

// Round 8
// 100.909 us; speedup vs baseline: 1.4551x; 1.4551x over previous
//
#include <hip/hip_runtime.h>
#include <hip/hip_bf16.h>

typedef __attribute__((ext_vector_type(8))) short short8;
typedef __attribute__((ext_vector_type(4))) float f32x4;

#define LSTR 268  // f32 row stride for A/C: 1072B rows -> 16B-aligned, <=2-way banks

__device__ __forceinline__ unsigned short f2bf_rne(float x) {
  unsigned u = __float_as_uint(x);
  return (unsigned short)((u + 0x7FFFu + ((u >> 16) & 1u)) >> 16);
}

// scalar cast the compiler fuses into v_cvt_pk_bf16_f32 pairs (m240)
__device__ __forceinline__ short bfc(float x) {
  __hip_bfloat16 h = __float2bfloat16(x);
  return __builtin_bit_cast(short, h);
}

// ---- prep: weights -> bf16, fragment-transposed into d_ws (once per launch) ----
__global__ __launch_bounds__(256) void prep_kernel(
    const float* __restrict__ gW0, const float* __restrict__ gW1,
    unsigned short* __restrict__ W0T, unsigned short* __restrict__ W1T)
{
  const int t = blockIdx.x * 256 + threadIdx.x;  // 0..65535
  {
    const int c = t >> 7, k = t & 127;
    const int src = (k + ((c >= 256) ? 128 : 0)) * 256 + (c & 255);
    W0T[t] = f2bf_rne(gW0[src]);
  }
  {
    const int n = t >> 8, k = t & 255;
    W1T[t] = f2bf_rne(gW1[k * 256 + n]);
  }
}

// ---- main: per-batch pair MLP + pooled sum ----
// Rounds 3-7 lesson: the compiler targets ~128 arch-VGPRs because
// __launch_bounds__' 2nd arg only sets a MINIMUM waves/EU -- it remats weight
// loads into the loop (r3/r5) or spills accumulators (r6/r7) to hit that
// target. amdgpu_waves_per_eu(2,2) bounds occupancy from ABOVE, telling the
// allocator 2 waves/SIMD is all there will ever be -> ~240 VGPRs usable ->
// bw[4][8] (128) + creg[16] (64) + acc (16) stay genuinely resident and the
// phase-3 loop is pure ds_read(bcast) -> ~20 VALU -> 4 MFMA. Zero VMEM.
__global__ __attribute__((amdgpu_flat_work_group_size(256, 256),
                          amdgpu_waves_per_eu(2, 2)))
void pair_kernel(
    const float* __restrict__ state,
    const unsigned short* __restrict__ W0T, const float* __restrict__ gb0,
    const unsigned short* __restrict__ W1T, const float* __restrict__ gb1,
    float* __restrict__ pooled)
{
  const int b   = blockIdx.x;
  const int tid = threadIdx.x;
  const int w   = tid >> 6;   // wave 0..3
  const int l   = tid & 63;
  const int lr  = l & 15;
  const int lg  = l >> 4;

  __shared__ float A_lds[16 * LSTR];
  __shared__ float C_lds[16 * LSTR];

  const float* stb = state + (size_t)b * 2048;

  // ---------------- Phase 2: [A|C] = state[16x128] @ W0 ----------------
  short8 sfrag[4];
  #pragma unroll
  for (int kk = 0; kk < 4; ++kk) {
    const float* sp = stb + lr * 128 + kk * 32 + lg * 8;
    f32x4 s0 = *(const f32x4*)sp;
    f32x4 s1 = *(const f32x4*)(sp + 4);
    short8 f;
    f[0] = bfc(s0[0]); f[1] = bfc(s0[1]); f[2] = bfc(s0[2]); f[3] = bfc(s0[3]);
    f[4] = bfc(s1[0]); f[5] = bfc(s1[1]); f[6] = bfc(s1[2]); f[7] = bfc(s1[3]);
    sfrag[kk] = f;
  }

  const f32x4 z4 = {0.f, 0.f, 0.f, 0.f};
  f32x4 acc2[8];
  #pragma unroll
  for (int nt = 0; nt < 8; ++nt) acc2[nt] = z4;

  #pragma unroll
  for (int nt = 0; nt < 8; ++nt) {
    const int col = 128 * w + 16 * nt + lr;       // [A|C] col in [0,512)
    #pragma unroll
    for (int kk = 0; kk < 4; ++kk) {
      short8 bf = *(const short8*)(W0T + (size_t)col * 128 + kk * 32 + lg * 8);
      acc2[nt] = __builtin_amdgcn_mfma_f32_16x16x32_bf16(sfrag[kk], bf, acc2[nt], 0, 0, 0);
    }
  }

  // gW1 fragments (wave w owns N-cols [64w,64w+64)) -> resident for phase 3
  short8 bw[4][8];
  #pragma unroll
  for (int nt = 0; nt < 4; ++nt) {
    const int n = 64 * w + 16 * nt + lr;
    #pragma unroll
    for (int kk = 0; kk < 8; ++kk)
      bw[nt][kk] = *(const short8*)(W1T + (size_t)n * 256 + kk * 32 + lg * 8);
  }
  float gb1v[4];
  #pragma unroll
  for (int nt = 0; nt < 4; ++nt) gb1v[nt] = gb1[64 * w + 16 * nt + lr];

  // store phase-2 results (C/D layout: col=lr, row=lg*4+r)
  #pragma unroll
  for (int nt = 0; nt < 8; ++nt) {
    const int col = 128 * w + 16 * nt + lr;
    #pragma unroll
    for (int r = 0; r < 4; ++r) {
      const int row = lg * 4 + r;
      float v = acc2[nt][r];
      if (col < 256) A_lds[row * LSTR + col]       = v + gb0[col];  // fold gb0
      else           C_lds[row * LSTR + col - 256] = v;
    }
  }
  __syncthreads();

  // C rows -> registers: lane (lr,lg) holds C[lr][kk*32+lg*8 .. +8], kk=0..7
  f32x4 creg[16];
  #pragma unroll
  for (int kk = 0; kk < 8; ++kk) {
    const float* cp = &C_lds[lr * LSTR + kk * 32 + lg * 8];
    creg[2 * kk]     = *(const f32x4*)cp;
    creg[2 * kk + 1] = *(const f32x4*)(cp + 4);
  }

  // ---------------- Phase 3: tile = fixed i, rows = j (mask j==i) ----------------
  // pure ds_read(bcast) -> ~20 VALU -> 4 independent MFMA chains. Zero VMEM.
  float pp[4] = {0.f, 0.f, 0.f, 0.f};
  #pragma unroll 1
  for (int i = 0; i < 16; ++i) {
    f32x4 acc[4];
    #pragma unroll
    for (int nt = 0; nt < 4; ++nt) acc[nt] = z4;

    #pragma unroll
    for (int kk = 0; kk < 8; ++kk) {
      const float* ap = &A_lds[i * LSTR + kk * 32 + lg * 8];  // wave-uniform bcast
      f32x4 a0 = *(const f32x4*)ap;
      f32x4 a1 = *(const f32x4*)(ap + 4);
      f32x4 s0 = __builtin_elementwise_max(a0 + creg[2 * kk],     z4);
      f32x4 s1 = __builtin_elementwise_max(a1 + creg[2 * kk + 1], z4);
      short8 u;
      u[0] = bfc(s0[0]); u[1] = bfc(s0[1]); u[2] = bfc(s0[2]); u[3] = bfc(s0[3]);
      u[4] = bfc(s1[0]); u[5] = bfc(s1[1]); u[6] = bfc(s1[2]); u[7] = bfc(s1[3]);
      #pragma unroll
      for (int nt = 0; nt < 4; ++nt)
        acc[nt] = __builtin_amdgcn_mfma_f32_16x16x32_bf16(u, bw[nt][kk], acc[nt], 0, 0, 0);
    }

    #pragma unroll
    for (int nt = 0; nt < 4; ++nt) {
      #pragma unroll
      for (int r4 = 0; r4 < 4; ++r4) {
        const int row = lg * 4 + r4;       // = j
        const float v = fmaxf(acc[nt][r4] + gb1v[nt], 0.f);
        pp[nt] += (row == i) ? 0.f : v;    // mask the (i,i) filler pair
      }
    }
  }

  // reduce the 4 lane-groups (disjoint row subsets, same col), write pooled
  #pragma unroll
  for (int nt = 0; nt < 4; ++nt) {
    float v = pp[nt];
    v += __shfl_xor(v, 16);
    v += __shfl_xor(v, 32);
    if (lg == 0) pooled[(size_t)b * 256 + 64 * w + 16 * nt + lr] = v;
  }
}

// ---- f-MLP: 8 batches per block -> 8x weight reuse per load ----
__global__ __launch_bounds__(256) void fmlp_kernel(
    const float* __restrict__ pooled,
    const float* __restrict__ fW0, const float* __restrict__ fb0,
    const float* __restrict__ fW1, const float* __restrict__ fb1,
    float* __restrict__ out)
{
  const int tid = threadIdx.x;
  const size_t b0 = (size_t)blockIdx.x * 8;
  __shared__ float pl[8][256];
  __shared__ float h1[8][256];

  #pragma unroll
  for (int q = 0; q < 8; ++q) {
    const int idx = q * 256 + tid;
    pl[idx >> 8][idx & 255] = pooled[b0 * 256 + idx];
  }
  __syncthreads();

  float acc[8] = {0.f, 0.f, 0.f, 0.f, 0.f, 0.f, 0.f, 0.f};
  #pragma unroll 4
  for (int k = 0; k < 256; ++k) {
    const float wv = fW0[(size_t)k * 256 + tid];
    #pragma unroll
    for (int q = 0; q < 8; ++q) acc[q] = fmaf(pl[q][k], wv, acc[q]);
  }
  #pragma unroll
  for (int q = 0; q < 8; ++q) h1[q][tid] = fmaxf(acc[q] + fb0[tid], 0.f);
  __syncthreads();

  float acc2[8] = {0.f, 0.f, 0.f, 0.f, 0.f, 0.f, 0.f, 0.f};
  #pragma unroll 4
  for (int k = 0; k < 256; ++k) {
    const float wv = fW1[(size_t)k * 256 + tid];
    #pragma unroll
    for (int q = 0; q < 8; ++q) acc2[q] = fmaf(h1[q][k], wv, acc2[q]);
  }
  #pragma unroll
  for (int q = 0; q < 8; ++q)
    out[(b0 + q) * 256 + tid] = fmaxf(acc2[q] + fb1[tid], 0.f);
}

extern "C" void kernel_launch(void* const* d_in, const int* in_sizes, int n_in,
                              void* d_out, int out_size, void* d_ws, size_t ws_size,
                              hipStream_t stream) {
  const float* state = (const float*)d_in[0];
  const float* gW0   = (const float*)d_in[1];
  const float* gb0   = (const float*)d_in[2];
  const float* gW1   = (const float*)d_in[3];
  const float* gb1   = (const float*)d_in[4];
  const float* fW0   = (const float*)d_in[5];
  const float* fb0   = (const float*)d_in[6];
  const float* fW1   = (const float*)d_in[7];
  const float* fb1   = (const float*)d_in[8];
  float* out = (float*)d_out;

  unsigned short* W0T = (unsigned short*)d_ws;          // 512*128 bf16 = 128KB
  unsigned short* W1T = W0T + 512 * 128;                // 256*256 bf16 = 128KB
  float* pooled = (float*)(W1T + 256 * 256);            // 1024*256 f32 = 1MB

  const int Bn = in_sizes[0] / 2048;  // 1024

  prep_kernel<<<dim3(256), dim3(256), 0, stream>>>(gW0, gW1, W0T, W1T);
  pair_kernel<<<dim3(Bn), dim3(256), 0, stream>>>(state, W0T, gb0, W1T, gb1, pooled);
  fmlp_kernel<<<dim3(Bn / 8), dim3(256), 0, stream>>>(pooled, fW0, fb0, fW1, fb1, out);
}